// Round 15
// baseline (232.830 us; speedup 1.0000x reference)
//
#include <hip/hip_runtime.h>
#include <hip/hip_bf16.h>

#define KDIM 128

typedef __attribute__((ext_vector_type(8))) __bf16 bf16x8;
typedef __attribute__((ext_vector_type(4))) float f32x4;
typedef __attribute__((ext_vector_type(2))) float f32x2;

// bf16 pack via explicit bit ops.
static __device__ __forceinline__ unsigned short f2bf(float f) {
  unsigned u = __float_as_uint(f);
  u += 0x7fffu + ((u >> 16) & 1u);        // round-to-nearest-even
  return (unsigned short)(u >> 16);
}
static __device__ __forceinline__ unsigned pack_bf16x2(float a, float b) {
  return (unsigned)f2bf(a) | ((unsigned)f2bf(b) << 16);
}
// ReLU on a packed pair of bf16.
static __device__ __forceinline__ unsigned relu2(unsigned u) {
  unsigned r = u;
  if (u & 0x00008000u) r &= 0xffff0000u;
  if (u & 0x80000000u) r &= 0x0000ffffu;
  return r;
}

// ---------------------------------------------------------------------------
// fp8 (OCP e4m3fn) encode/decode. HW cvt if available, software fallback.
// ---------------------------------------------------------------------------
static __device__ __forceinline__ unsigned char f2fp8(float f) {
#if __has_builtin(__builtin_amdgcn_cvt_pk_fp8_f32)
  return (unsigned char)(__builtin_amdgcn_cvt_pk_fp8_f32(f, f, 0, false) & 0xff);
#else
  unsigned s = (__float_as_uint(f) >> 24) & 0x80u;
  float a = fminf(fabsf(f), 448.f);
  if (a < 0.015625f) {
    unsigned m = (unsigned)(a * 512.f + 0.5f);
    return (unsigned char)(s | m);
  }
  unsigned v = __float_as_uint(a);
  v += 0x7ffffu + ((v >> 20) & 1u);
  unsigned em = (v >> 20) - 960u;
  if (em > 0x7eu) em = 0x7eu;
  return (unsigned char)(s | em);
#endif
}
static __device__ __forceinline__ float fp8dec(unsigned b) {
  unsigned s = (b & 0x80u) << 24;
  unsigned em = b & 0x7fu;
  float mag = (em >= 8) ? __uint_as_float((em + 960u) << 20)
                        : (float)em * 0.001953125f;
  return __uint_as_float(__float_as_uint(mag) | s);
}
static __device__ __forceinline__ float4 fp8x4_to_f32(unsigned u) {
#if __has_builtin(__builtin_amdgcn_cvt_pk_f32_fp8)
  f32x2 lo = __builtin_amdgcn_cvt_pk_f32_fp8(u, false);
  f32x2 hi = __builtin_amdgcn_cvt_pk_f32_fp8(u, true);
  return make_float4(lo[0], lo[1], hi[0], hi[1]);
#else
  return make_float4(fp8dec(u & 255u), fp8dec((u >> 8) & 255u),
                     fp8dec((u >> 16) & 255u), fp8dec(u >> 24));
#endif
}

// 64-lane exclusive scan of bsum[0..nb-1] (nb<=64) into bl[]; all threads sync.
static __device__ __forceinline__ void local_bscan(const int* __restrict__ bsum,
                                                   int nb, int* bl) {
  if (threadIdx.x < 64) {
    const int t = threadIdx.x;
    const int v = (t < nb) ? bsum[t] : 0;
    int x = v;
    #pragma unroll
    for (int off = 1; off < 64; off <<= 1) {
      const int y = __shfl_up(x, off, 64);
      if (t >= off) x += y;
    }
    bl[t] = x - v;
  }
  __syncthreads();
}

// ---------------------------------------------------------------------------
// MFMA GEMM body: C[M,NOUT](fp8) = act(A[M,128]) @ W, Wt[n][k] bf16 in global.
// ---------------------------------------------------------------------------
template<int NOUT, bool AF32, bool RELU>
static __device__ __forceinline__ void gemm_body(const void* __restrict__ Av,
                                                 const unsigned short* __restrict__ Wt,
                                                 unsigned char* __restrict__ C, int M,
                                                 int bx,
                                                 unsigned short (*Ws)[136]) {
  constexpr int NT = NOUT / 16;
  const int tid = threadIdx.x;
  for (int i = tid; i < NOUT * 16; i += 512) {
    const int n = i >> 4, k8 = i & 15;
    const uint4 v = *reinterpret_cast<const uint4*>(&Wt[n * KDIM + k8 * 8]);
    *reinterpret_cast<uint4*>(&Ws[n][k8 * 8]) = v;
  }

  const int wv = tid >> 6;
  const int l  = tid & 63;
  const int am = l & 15;
  const int kb = l >> 4;
  const int arow_g = bx * 128 + wv * 16 + am;
  const bool valid = arow_g < M;
  const int arow = valid ? arow_g : 0;

  uint4 afr[4];
  if constexpr (AF32) {
    const float* A = (const float*)Av;
    #pragma unroll
    for (int ks = 0; ks < 4; ++ks) {
      const float4 lo = *reinterpret_cast<const float4*>(&A[(size_t)arow * 128 + ks * 32 + kb * 8]);
      const float4 hi = *reinterpret_cast<const float4*>(&A[(size_t)arow * 128 + ks * 32 + kb * 8 + 4]);
      afr[ks] = make_uint4(pack_bf16x2(lo.x, lo.y), pack_bf16x2(lo.z, lo.w),
                           pack_bf16x2(hi.x, hi.y), pack_bf16x2(hi.z, hi.w));
    }
  } else {
    const unsigned* A = (const unsigned*)Av;
    #pragma unroll
    for (int ks = 0; ks < 4; ++ks) {
      uint4 u = *reinterpret_cast<const uint4*>(&A[(size_t)arow * 64 + ks * 16 + kb * 4]);
      if constexpr (RELU) {
        u.x = relu2(u.x); u.y = relu2(u.y); u.z = relu2(u.z); u.w = relu2(u.w);
      }
      afr[ks] = u;
    }
  }
  if (!valid) {
    afr[0] = make_uint4(0, 0, 0, 0); afr[1] = afr[0];
    afr[2] = afr[0];                 afr[3] = afr[0];
  }

  f32x4 acc[NT];
  #pragma unroll
  for (int nt = 0; nt < NT; ++nt) {
    acc[nt][0] = 0.f; acc[nt][1] = 0.f; acc[nt][2] = 0.f; acc[nt][3] = 0.f;
  }

  __syncthreads();
  #pragma unroll
  for (int ks = 0; ks < 4; ++ks) {
    const bf16x8 a = __builtin_bit_cast(bf16x8, afr[ks]);
    #pragma unroll
    for (int nt = 0; nt < NT; ++nt) {
      const uint4 bv = *reinterpret_cast<const uint4*>(&Ws[nt * 16 + am][ks * 32 + kb * 8]);
      acc[nt] = __builtin_amdgcn_mfma_f32_16x16x32_bf16(
          a, __builtin_bit_cast(bf16x8, bv), acc[nt], 0, 0, 0);
    }
  }

  const int crow0 = bx * 128 + wv * 16 + kb * 4;
  #pragma unroll
  for (int nt = 0; nt < NT; ++nt) {
    #pragma unroll
    for (int r = 0; r < 4; ++r) {
      const int rr = crow0 + r;
      if (rr < M) C[(size_t)rr * NOUT + nt * 16 + am] = f2fp8(acc[nt][r]);
    }
  }
}

template<int NOUT, bool AF32, bool RELU>
__global__ __launch_bounds__(512) void gemm_mfma_k(const void* __restrict__ Av,
                                                   const unsigned short* __restrict__ Wt,
                                                   unsigned char* __restrict__ C, int M) {
  __shared__ unsigned short Ws[NOUT][136];
  gemm_body<NOUT, AF32, RELU>(Av, Wt, C, M, blockIdx.x, Ws);
}

// ---------------------------------------------------------------------------
// binscatter body: re-read edges, write packed (dstLocal<<17|src) into
// bin-grouped epack via LDS cursors. lds = [cur 512 | bl 64] ints.
// ---------------------------------------------------------------------------
static __device__ __forceinline__ void binscatter_body(const int* __restrict__ src,
                                                       const int* __restrict__ dst,
                                                       const int* __restrict__ histOff,
                                                       const int* __restrict__ bsum,
                                                       int nb,
                                                       unsigned* __restrict__ epack,
                                                       int E, int nbins, int bid,
                                                       int* lds) {
  int* cur = lds;
  int* bl  = lds + 512;
  local_bscan(bsum, nb, bl);
  for (int i = threadIdx.x; i < nbins; i += 512) {
    const int gi = i * 256 + bid;
    cur[i] = histOff[gi] + bl[gi >> 11];
  }
  __syncthreads();
  const int E4 = E >> 2;
  for (int i = bid * 512 + threadIdx.x; i < E4; i += 256 * 512) {
    const int4 d4 = *reinterpret_cast<const int4*>(&dst[i * 4]);
    const int4 s4 = *reinterpret_cast<const int4*>(&src[i * 4]);
    int p;
    p = atomicAdd(&cur[d4.x >> 8], 1); epack[p] = ((unsigned)(d4.x & 255) << 17) | (unsigned)s4.x;
    p = atomicAdd(&cur[d4.y >> 8], 1); epack[p] = ((unsigned)(d4.y & 255) << 17) | (unsigned)s4.y;
    p = atomicAdd(&cur[d4.z >> 8], 1); epack[p] = ((unsigned)(d4.z & 255) << 17) | (unsigned)s4.z;
    p = atomicAdd(&cur[d4.w >> 8], 1); epack[p] = ((unsigned)(d4.w & 255) << 17) | (unsigned)s4.w;
  }
  if (bid == 0 && threadIdx.x < (E & 3)) {
    const int e = E4 * 4 + threadIdx.x;
    const int d = dst[e];
    const int p = atomicAdd(&cur[d >> 8], 1);
    epack[p] = ((unsigned)(d & 255) << 17) | (unsigned)src[e];
  }
}

// ---------------------------------------------------------------------------
// Mega kernel: blocks [0,gemm_grid) = layer-1 GEMM; [gemm_grid,+256) =
// binscatter. Independent work, different bottlenecks -> overlap.
// ---------------------------------------------------------------------------
__global__ __launch_bounds__(512) void mega1_k(const float* __restrict__ x,
                                               const unsigned short* __restrict__ Wt1,
                                               unsigned char* __restrict__ H, int M,
                                               const int* __restrict__ src,
                                               const int* __restrict__ dst,
                                               const int* __restrict__ histOff,
                                               const int* __restrict__ bsum,
                                               int nb,
                                               unsigned* __restrict__ epack,
                                               int E, int nbins, int gemm_grid) {
  __shared__ unsigned short Ws[128][136];
  if ((int)blockIdx.x < gemm_grid) {
    gemm_body<128, true, false>(x, Wt1, H, M, blockIdx.x, Ws);
  } else {
    binscatter_body(src, dst, histOff, bsum, nb, epack, E, nbins,
                    blockIdx.x - gemm_grid, (int*)&Ws[0][0]);
  }
}

// ---------------------------------------------------------------------------
// hist (+ fused W transpose). bin = dst >> 8 (256 nodes/bin, <=512 bins).
// ---------------------------------------------------------------------------
__global__ __launch_bounds__(512) void histw_k(const int* __restrict__ dst,
                                               int* __restrict__ histT,
                                               int E, int nbins,
                                               const float* __restrict__ W1,
                                               const float* __restrict__ W2,
                                               const float* __restrict__ W3,
                                               unsigned short* __restrict__ Wt) {
  if (threadIdx.x < 160) {
    const int t = blockIdx.x * 160 + threadIdx.x;
    if (t < 16384) {
      Wt[t] = f2bf(W1[(t & 127) * 128 + (t >> 7)]);
    } else if (t < 32768) {
      const int u = t - 16384;
      Wt[t] = f2bf(W2[(u & 127) * 128 + (u >> 7)]);
    } else if (t < 40960) {
      const int u = t - 32768;
      Wt[t] = f2bf(W3[(u & 127) * 64 + (u >> 7)]);
    }
  }

  __shared__ int h[512];
  for (int i = threadIdx.x; i < nbins; i += 512) h[i] = 0;
  __syncthreads();
  const int E4 = E >> 2;
  for (int i = blockIdx.x * 512 + threadIdx.x; i < E4; i += 256 * 512) {
    const int4 d4 = *reinterpret_cast<const int4*>(&dst[i * 4]);
    atomicAdd(&h[d4.x >> 8], 1);
    atomicAdd(&h[d4.y >> 8], 1);
    atomicAdd(&h[d4.z >> 8], 1);
    atomicAdd(&h[d4.w >> 8], 1);
  }
  if (blockIdx.x == 0 && threadIdx.x < (E & 3))
    atomicAdd(&h[dst[E4 * 4 + threadIdx.x] >> 8], 1);
  __syncthreads();
  for (int i = threadIdx.x; i < nbins; i += 512)
    histT[i * 256 + blockIdx.x] = h[i];
}

__global__ __launch_bounds__(256) void scan1_k(const int* __restrict__ in,
                                               int* __restrict__ out,
                                               int* __restrict__ bsum, int N) {
  __shared__ int ls[256];
  const int t = threadIdx.x;
  const int base = blockIdx.x * 2048 + t * 8;
  int v[8];
  if (base + 8 <= N) {
    *reinterpret_cast<int4*>(&v[0]) = *reinterpret_cast<const int4*>(&in[base]);
    *reinterpret_cast<int4*>(&v[4]) = *reinterpret_cast<const int4*>(&in[base + 4]);
  } else {
    #pragma unroll
    for (int j = 0; j < 8; ++j) v[j] = (base + j < N) ? in[base + j] : 0;
  }
  int s = 0;
  #pragma unroll
  for (int j = 0; j < 8; ++j) { const int tmp = v[j]; v[j] = s; s += tmp; }
  int x = s;
  ls[t] = x;
  __syncthreads();
  for (int off = 1; off < 256; off <<= 1) {
    int y = 0;
    if (t >= off) y = ls[t - off];
    __syncthreads();
    x += y;
    ls[t] = x;
    __syncthreads();
  }
  const int excl = x - s;
  #pragma unroll
  for (int j = 0; j < 8; ++j)
    if (base + j < N) out[base + j] = excl + v[j];
  if (t == 255) bsum[blockIdx.x] = x;
}

// binsort: one block per 256-node bin; local bscan; 256-counter LDS histogram
// + scan -> rowptr, then LDS-cursor scatter of src into col.
__global__ __launch_bounds__(512) void binsort_k(const unsigned* __restrict__ epack,
                                                 const int* __restrict__ histOff,
                                                 const int* __restrict__ bsum,
                                                 int nb,
                                                 int* __restrict__ rowptr,
                                                 int* __restrict__ col,
                                                 int N, int E, int nbins) {
  __shared__ int hist[256];
  __shared__ int ls[256];
  __shared__ int cur[256];
  __shared__ int bl[64];
  const int b = blockIdx.x;
  const int t = threadIdx.x;
  local_bscan(bsum, nb, bl);
  const int i0 = b * 256;
  const int beg = histOff[i0] + bl[i0 >> 11];
  int end = E;
  if (b + 1 < nbins) {
    const int i1 = (b + 1) * 256;
    end = histOff[i1] + bl[i1 >> 11];
  }

  if (t < 256) hist[t] = 0;
  __syncthreads();
  for (int j = beg + t; j < end; j += 512)
    atomicAdd(&hist[epack[j] >> 17], 1);
  __syncthreads();

  int v = 0, x = 0;
  if (t < 256) { v = hist[t]; x = v; ls[t] = x; }
  __syncthreads();
  for (int off = 1; off < 256; off <<= 1) {
    int y = 0;
    if (t < 256 && t >= off) y = ls[t - off];
    __syncthreads();
    if (t < 256) { x += y; ls[t] = x; }
    __syncthreads();
  }
  if (t < 256) {
    const int excl = x - v;
    cur[t] = excl;
    const int g = b * 256 + t;
    if (g <= N) rowptr[g] = beg + excl;
  }
  if (b == nbins - 1 && t == 0) rowptr[N] = E;
  __syncthreads();
  for (int j = beg + t; j < end; j += 512) {
    const unsigned p = epack[j];
    const int pos = atomicAdd(&cur[p >> 17], 1);
    col[beg + pos] = (int)(p & 0x1ffffu);
  }
}

// ---------------------------------------------------------------------------
// Gather-aggregate, D=128 fp8 rows (128B). Quarter-wave per edge; lane loads
// uint2 (8 fp8), 16 lanes cover a row. col loads non-temporal (streamed once).
// ---------------------------------------------------------------------------
__global__ __launch_bounds__(256) void gather128_k(const uint2* __restrict__ H64,
                                                   const int* __restrict__ rowptr,
                                                   const int* __restrict__ col,
                                                   unsigned* __restrict__ out, int N) {
  const int w = (int)((blockIdx.x * 256u + threadIdx.x) >> 6);
  const int lane = threadIdx.x & 63;
  const int q = lane >> 4;                // quarter 0..3
  const int l4 = lane & 15;               // uint2 index within row (16 x 8B = 128B)
  if (w >= N) return;
  const int beg = __builtin_amdgcn_readfirstlane(rowptr[w]);
  const int end = __builtin_amdgcn_readfirstlane(rowptr[w + 1]);

  float4 a0A = make_float4(0.f, 0.f, 0.f, 0.f), a0B = make_float4(0.f, 0.f, 0.f, 0.f);
  float4 a1A = make_float4(0.f, 0.f, 0.f, 0.f), a1B = make_float4(0.f, 0.f, 0.f, 0.f);

  int e = beg;
  for (; e + 16 <= end; e += 16) {
    const int s0 = __builtin_nontemporal_load(&col[e + q]);
    const int s1 = __builtin_nontemporal_load(&col[e + 4 + q]);
    const int s2 = __builtin_nontemporal_load(&col[e + 8 + q]);
    const int s3 = __builtin_nontemporal_load(&col[e + 12 + q]);
    const uint2 u0 = H64[(size_t)s0 * 16 + l4];
    const uint2 u1 = H64[(size_t)s1 * 16 + l4];
    const uint2 u2 = H64[(size_t)s2 * 16 + l4];
    const uint2 u3 = H64[(size_t)s3 * 16 + l4];
    float4 v;
    v = fp8x4_to_f32(u0.x); a0A.x += v.x; a0A.y += v.y; a0A.z += v.z; a0A.w += v.w;
    v = fp8x4_to_f32(u0.y); a0B.x += v.x; a0B.y += v.y; a0B.z += v.z; a0B.w += v.w;
    v = fp8x4_to_f32(u1.x); a1A.x += v.x; a1A.y += v.y; a1A.z += v.z; a1A.w += v.w;
    v = fp8x4_to_f32(u1.y); a1B.x += v.x; a1B.y += v.y; a1B.z += v.z; a1B.w += v.w;
    v = fp8x4_to_f32(u2.x); a0A.x += v.x; a0A.y += v.y; a0A.z += v.z; a0A.w += v.w;
    v = fp8x4_to_f32(u2.y); a0B.x += v.x; a0B.y += v.y; a0B.z += v.z; a0B.w += v.w;
    v = fp8x4_to_f32(u3.x); a1A.x += v.x; a1A.y += v.y; a1A.z += v.z; a1A.w += v.w;
    v = fp8x4_to_f32(u3.y); a1B.x += v.x; a1B.y += v.y; a1B.z += v.z; a1B.w += v.w;
  }
  for (; e + 4 <= end; e += 4) {
    const int s = __builtin_nontemporal_load(&col[e + q]);
    const uint2 u = H64[(size_t)s * 16 + l4];
    float4 v;
    v = fp8x4_to_f32(u.x); a0A.x += v.x; a0A.y += v.y; a0A.z += v.z; a0A.w += v.w;
    v = fp8x4_to_f32(u.y); a0B.x += v.x; a0B.y += v.y; a0B.z += v.z; a0B.w += v.w;
  }
  if (q < end - e) {
    const int s = __builtin_nontemporal_load(&col[e + q]);
    const uint2 u = H64[(size_t)s * 16 + l4];
    float4 v;
    v = fp8x4_to_f32(u.x); a1A.x += v.x; a1A.y += v.y; a1A.z += v.z; a1A.w += v.w;
    v = fp8x4_to_f32(u.y); a1B.x += v.x; a1B.y += v.y; a1B.z += v.z; a1B.w += v.w;
  }

  float4 aA, aB;
  aA.x = a0A.x + a1A.x; aA.y = a0A.y + a1A.y;
  aA.z = a0A.z + a1A.z; aA.w = a0A.w + a1A.w;
  aB.x = a0B.x + a1B.x; aB.y = a0B.y + a1B.y;
  aB.z = a0B.z + a1B.z; aB.w = a0B.w + a1B.w;

  aA.x += __shfl_xor(aA.x, 16, 64); aA.x += __shfl_xor(aA.x, 32, 64);
  aA.y += __shfl_xor(aA.y, 16, 64); aA.y += __shfl_xor(aA.y, 32, 64);
  aA.z += __shfl_xor(aA.z, 16, 64); aA.z += __shfl_xor(aA.z, 32, 64);
  aA.w += __shfl_xor(aA.w, 16, 64); aA.w += __shfl_xor(aA.w, 32, 64);
  aB.x += __shfl_xor(aB.x, 16, 64); aB.x += __shfl_xor(aB.x, 32, 64);
  aB.y += __shfl_xor(aB.y, 16, 64); aB.y += __shfl_xor(aB.y, 32, 64);
  aB.z += __shfl_xor(aB.z, 16, 64); aB.z += __shfl_xor(aB.z, 32, 64);
  aB.w += __shfl_xor(aB.w, 16, 64); aB.w += __shfl_xor(aB.w, 32, 64);

  if (q == 0) {
    const uint4 pk = make_uint4(pack_bf16x2(aA.x, aA.y), pack_bf16x2(aA.z, aA.w),
                                pack_bf16x2(aB.x, aB.y), pack_bf16x2(aB.z, aB.w));
    *reinterpret_cast<uint4*>(&out[(size_t)w * 64 + l4 * 4]) = pk;
  }
}

// ---------------------------------------------------------------------------
// Gather-aggregate D=64 fp8 rows (64B) + fused log_softmax.
// ---------------------------------------------------------------------------
__global__ __launch_bounds__(256) void gather64lsm_k(const unsigned* __restrict__ H32,
                                                     const int* __restrict__ rowptr,
                                                     const int* __restrict__ col,
                                                     float* __restrict__ out, int N) {
  const int w = (int)((blockIdx.x * 256u + threadIdx.x) >> 6);
  const int lane = threadIdx.x & 63;
  const int q = lane >> 4;
  const int l4 = lane & 15;
  if (w >= N) return;
  const int beg = __builtin_amdgcn_readfirstlane(rowptr[w]);
  const int end = __builtin_amdgcn_readfirstlane(rowptr[w + 1]);

  float4 acc0 = make_float4(0.f, 0.f, 0.f, 0.f);
  float4 acc1 = make_float4(0.f, 0.f, 0.f, 0.f);

  int e = beg;
  for (; e + 16 <= end; e += 16) {
    const int s0 = __builtin_nontemporal_load(&col[e + q]);
    const int s1 = __builtin_nontemporal_load(&col[e + 4 + q]);
    const int s2 = __builtin_nontemporal_load(&col[e + 8 + q]);
    const int s3 = __builtin_nontemporal_load(&col[e + 12 + q]);
    const unsigned u0 = H32[(size_t)s0 * 16 + l4];
    const unsigned u1 = H32[(size_t)s1 * 16 + l4];
    const unsigned u2 = H32[(size_t)s2 * 16 + l4];
    const unsigned u3 = H32[(size_t)s3 * 16 + l4];
    float4 v;
    v = fp8x4_to_f32(u0); acc0.x += v.x; acc0.y += v.y; acc0.z += v.z; acc0.w += v.w;
    v = fp8x4_to_f32(u1); acc1.x += v.x; acc1.y += v.y; acc1.z += v.z; acc1.w += v.w;
    v = fp8x4_to_f32(u2); acc0.x += v.x; acc0.y += v.y; acc0.z += v.z; acc0.w += v.w;
    v = fp8x4_to_f32(u3); acc1.x += v.x; acc1.y += v.y; acc1.z += v.z; acc1.w += v.w;
  }
  for (; e + 8 <= end; e += 8) {
    const int s0 = __builtin_nontemporal_load(&col[e + q]);
    const int s1 = __builtin_nontemporal_load(&col[e + 4 + q]);
    const float4 v0 = fp8x4_to_f32(H32[(size_t)s0 * 16 + l4]);
    const float4 v1 = fp8x4_to_f32(H32[(size_t)s1 * 16 + l4]);
    acc0.x += v0.x; acc0.y += v0.y; acc0.z += v0.z; acc0.w += v0.w;
    acc1.x += v1.x; acc1.y += v1.y; acc1.z += v1.z; acc1.w += v1.w;
  }
  if (e + 4 <= end) {
    const int s = __builtin_nontemporal_load(&col[e + q]);
    const float4 v = fp8x4_to_f32(H32[(size_t)s * 16 + l4]);
    acc0.x += v.x; acc0.y += v.y; acc0.z += v.z; acc0.w += v.w;
    e += 4;
  }
  if (e + q < end) {
    const int s = __builtin_nontemporal_load(&col[e + q]);
    const float4 v = fp8x4_to_f32(H32[(size_t)s * 16 + l4]);
    acc1.x += v.x; acc1.y += v.y; acc1.z += v.z; acc1.w += v.w;
  }

  float4 a;
  a.x = acc0.x + acc1.x;
  a.y = acc0.y + acc1.y;
  a.z = acc0.z + acc1.z;
  a.w = acc0.w + acc1.w;
  a.x += __shfl_xor(a.x, 16, 64); a.x += __shfl_xor(a.x, 32, 64);
  a.y += __shfl_xor(a.y, 16, 64); a.y += __shfl_xor(a.y, 32, 64);
  a.z += __shfl_xor(a.z, 16, 64); a.z += __shfl_xor(a.z, 32, 64);
  a.w += __shfl_xor(a.w, 16, 64); a.w += __shfl_xor(a.w, 32, 64);

  float m = fmaxf(fmaxf(a.x, a.y), fmaxf(a.z, a.w));
  #pragma unroll
  for (int o = 8; o > 0; o >>= 1) m = fmaxf(m, __shfl_xor(m, o, 64));
  float s = __expf(a.x - m) + __expf(a.y - m) + __expf(a.z - m) + __expf(a.w - m);
  #pragma unroll
  for (int o = 8; o > 0; o >>= 1) s += __shfl_xor(s, o, 64);
  const float ls = __logf(s);

  if (lane < 16) {
    *reinterpret_cast<float4*>(&out[(size_t)w * 64 + l4 * 4]) =
        make_float4(a.x - m - ls, a.y - m - ls, a.z - m - ls, a.w - m - ls);
  }
}

extern "C" void kernel_launch(void* const* d_in, const int* in_sizes, int n_in,
                              void* d_out, int out_size, void* d_ws, size_t ws_size,
                              hipStream_t stream) {
  const float* x  = (const float*)d_in[0];
  const int*   ei = (const int*)d_in[1];
  const float* W1 = (const float*)d_in[2];
  const float* W2 = (const float*)d_in[3];
  const float* W3 = (const float*)d_in[4];
  float* out = (float*)d_out;

  const int N = in_sizes[0] / KDIM;       // 100000
  const int E = in_sizes[1] / 2;          // 1600000
  const int* src = ei;
  const int* dst = ei + E;

  const int nbins = (N + 255) / 256;      // 391
  const int ncells = nbins * 256;         // 100096
  const int scan_blocks = (ncells + 2047) / 2048;  // 49

  // Workspace layout (all chunks 16B-aligned)
  unsigned char* H = (unsigned char*)d_ws;              // [N,128] fp8
  unsigned* AGGp = (unsigned*)(H + (size_t)N * 128);    // [N,64] packed bf16 pairs
  unsigned short* Wt1 = (unsigned short*)(AGGp + (size_t)N * 64);  // [128,128]
  unsigned short* Wt2 = Wt1 + 128 * 128;                // [128,128]
  unsigned short* Wt3 = Wt2 + 128 * 128;                // [64,128]
  int* col     = (int*)(Wt3 + 64 * 128);                // [E]
  int* rowptr  = col + E;                               // [N+8]
  int* histT   = rowptr + (N + 8);                      // [<=131072]
  int* histOff = histT + 131072;                        // [<=131072]
  int* bsum2   = histOff + 131072;                      // [64]
  // epack (u32[E]) aliases AGGp (dead until layer-1 gather): E*4B <= N*64*4B
  unsigned* epack = (unsigned*)AGGp;

  const int gemm_grid = (N + 127) / 128;
  const int gather_grid = (N + 3) / 4;

  // ---- CSR build (with fused W transpose), then GEMM1 || binscatter ----
  histw_k<<<256, 512, 0, stream>>>(dst, histT, E, nbins, W1, W2, W3, Wt1);
  scan1_k<<<scan_blocks, 256, 0, stream>>>(histT, histOff, bsum2, ncells);
  mega1_k<<<gemm_grid + 256, 512, 0, stream>>>(x, Wt1, H, N, src, dst,
                                               histOff, bsum2, scan_blocks, epack,
                                               E, nbins, gemm_grid);
  binsort_k<<<nbins, 512, 0, stream>>>(epack, histOff, bsum2, scan_blocks,
                                       rowptr, col, N, E, nbins);

  // ---- layer 1 gather ----
  gather128_k<<<gather_grid, 256, 0, stream>>>((const uint2*)H, rowptr, col, AGGp, N);

  // ---- layer 2 ----
  gemm_mfma_k<128, false, true><<<gemm_grid, 512, 0, stream>>>(AGGp, Wt2, H, N);
  gather128_k<<<gather_grid, 256, 0, stream>>>((const uint2*)H, rowptr, col, AGGp, N);

  // ---- layer 3 (+ fused log_softmax) ----
  gemm_mfma_k<64, false, true><<<gemm_grid, 512, 0, stream>>>(AGGp, Wt3, H, N);
  gather64lsm_k<<<gather_grid, 256, 0, stream>>>((const unsigned*)H, rowptr, col, out, N);
}

// Round 16
// 208.950 us; speedup vs baseline: 1.1143x; 1.1143x over previous
//
#include <hip/hip_runtime.h>
#include <hip/hip_bf16.h>

#define KDIM 128

typedef __attribute__((ext_vector_type(8))) __bf16 bf16x8;
typedef __attribute__((ext_vector_type(4))) float f32x4;
typedef __attribute__((ext_vector_type(2))) float f32x2;

// bf16 pack via explicit bit ops.
static __device__ __forceinline__ unsigned short f2bf(float f) {
  unsigned u = __float_as_uint(f);
  u += 0x7fffu + ((u >> 16) & 1u);        // round-to-nearest-even
  return (unsigned short)(u >> 16);
}
static __device__ __forceinline__ unsigned pack_bf16x2(float a, float b) {
  return (unsigned)f2bf(a) | ((unsigned)f2bf(b) << 16);
}
// ReLU on a packed pair of bf16.
static __device__ __forceinline__ unsigned relu2(unsigned u) {
  unsigned r = u;
  if (u & 0x00008000u) r &= 0xffff0000u;
  if (u & 0x80000000u) r &= 0x0000ffffu;
  return r;
}

// ---------------------------------------------------------------------------
// fp8 (OCP e4m3fn) encode/decode. HW cvt if available, software fallback.
// ---------------------------------------------------------------------------
static __device__ __forceinline__ unsigned char f2fp8(float f) {
#if __has_builtin(__builtin_amdgcn_cvt_pk_fp8_f32)
  return (unsigned char)(__builtin_amdgcn_cvt_pk_fp8_f32(f, f, 0, false) & 0xff);
#else
  unsigned s = (__float_as_uint(f) >> 24) & 0x80u;
  float a = fminf(fabsf(f), 448.f);
  if (a < 0.015625f) {
    unsigned m = (unsigned)(a * 512.f + 0.5f);
    return (unsigned char)(s | m);
  }
  unsigned v = __float_as_uint(a);
  v += 0x7ffffu + ((v >> 20) & 1u);
  unsigned em = (v >> 20) - 960u;
  if (em > 0x7eu) em = 0x7eu;
  return (unsigned char)(s | em);
#endif
}
static __device__ __forceinline__ float fp8dec(unsigned b) {
  unsigned s = (b & 0x80u) << 24;
  unsigned em = b & 0x7fu;
  float mag = (em >= 8) ? __uint_as_float((em + 960u) << 20)
                        : (float)em * 0.001953125f;
  return __uint_as_float(__float_as_uint(mag) | s);
}
static __device__ __forceinline__ float4 fp8x4_to_f32(unsigned u) {
#if __has_builtin(__builtin_amdgcn_cvt_pk_f32_fp8)
  f32x2 lo = __builtin_amdgcn_cvt_pk_f32_fp8(u, false);
  f32x2 hi = __builtin_amdgcn_cvt_pk_f32_fp8(u, true);
  return make_float4(lo[0], lo[1], hi[0], hi[1]);
#else
  return make_float4(fp8dec(u & 255u), fp8dec((u >> 8) & 255u),
                     fp8dec((u >> 16) & 255u), fp8dec(u >> 24));
#endif
}

// 64-lane exclusive scan of bsum[0..nb-1] (nb<=64) into bl[]; all threads sync.
static __device__ __forceinline__ void local_bscan(const int* __restrict__ bsum,
                                                   int nb, int* bl) {
  if (threadIdx.x < 64) {
    const int t = threadIdx.x;
    const int v = (t < nb) ? bsum[t] : 0;
    int x = v;
    #pragma unroll
    for (int off = 1; off < 64; off <<= 1) {
      const int y = __shfl_up(x, off, 64);
      if (t >= off) x += y;
    }
    bl[t] = x - v;
  }
  __syncthreads();
}

// ---------------------------------------------------------------------------
// MFMA GEMM body: C[M,NOUT](fp8) = act(A[M,128]) @ W, Wt[n][k] bf16 in global.
// ---------------------------------------------------------------------------
template<int NOUT, bool AF32, bool RELU>
static __device__ __forceinline__ void gemm_body(const void* __restrict__ Av,
                                                 const unsigned short* __restrict__ Wt,
                                                 unsigned char* __restrict__ C, int M,
                                                 int bx,
                                                 unsigned short (*Ws)[136]) {
  constexpr int NT = NOUT / 16;
  const int tid = threadIdx.x;
  for (int i = tid; i < NOUT * 16; i += 512) {
    const int n = i >> 4, k8 = i & 15;
    const uint4 v = *reinterpret_cast<const uint4*>(&Wt[n * KDIM + k8 * 8]);
    *reinterpret_cast<uint4*>(&Ws[n][k8 * 8]) = v;
  }

  const int wv = tid >> 6;
  const int l  = tid & 63;
  const int am = l & 15;
  const int kb = l >> 4;
  const int arow_g = bx * 128 + wv * 16 + am;
  const bool valid = arow_g < M;
  const int arow = valid ? arow_g : 0;

  uint4 afr[4];
  if constexpr (AF32) {
    const float* A = (const float*)Av;
    #pragma unroll
    for (int ks = 0; ks < 4; ++ks) {
      const float4 lo = *reinterpret_cast<const float4*>(&A[(size_t)arow * 128 + ks * 32 + kb * 8]);
      const float4 hi = *reinterpret_cast<const float4*>(&A[(size_t)arow * 128 + ks * 32 + kb * 8 + 4]);
      afr[ks] = make_uint4(pack_bf16x2(lo.x, lo.y), pack_bf16x2(lo.z, lo.w),
                           pack_bf16x2(hi.x, hi.y), pack_bf16x2(hi.z, hi.w));
    }
  } else {
    const unsigned* A = (const unsigned*)Av;
    #pragma unroll
    for (int ks = 0; ks < 4; ++ks) {
      uint4 u = *reinterpret_cast<const uint4*>(&A[(size_t)arow * 64 + ks * 16 + kb * 4]);
      if constexpr (RELU) {
        u.x = relu2(u.x); u.y = relu2(u.y); u.z = relu2(u.z); u.w = relu2(u.w);
      }
      afr[ks] = u;
    }
  }
  if (!valid) {
    afr[0] = make_uint4(0, 0, 0, 0); afr[1] = afr[0];
    afr[2] = afr[0];                 afr[3] = afr[0];
  }

  f32x4 acc[NT];
  #pragma unroll
  for (int nt = 0; nt < NT; ++nt) {
    acc[nt][0] = 0.f; acc[nt][1] = 0.f; acc[nt][2] = 0.f; acc[nt][3] = 0.f;
  }

  __syncthreads();
  #pragma unroll
  for (int ks = 0; ks < 4; ++ks) {
    const bf16x8 a = __builtin_bit_cast(bf16x8, afr[ks]);
    #pragma unroll
    for (int nt = 0; nt < NT; ++nt) {
      const uint4 bv = *reinterpret_cast<const uint4*>(&Ws[nt * 16 + am][ks * 32 + kb * 8]);
      acc[nt] = __builtin_amdgcn_mfma_f32_16x16x32_bf16(
          a, __builtin_bit_cast(bf16x8, bv), acc[nt], 0, 0, 0);
    }
  }

  const int crow0 = bx * 128 + wv * 16 + kb * 4;
  #pragma unroll
  for (int nt = 0; nt < NT; ++nt) {
    #pragma unroll
    for (int r = 0; r < 4; ++r) {
      const int rr = crow0 + r;
      if (rr < M) C[(size_t)rr * NOUT + nt * 16 + am] = f2fp8(acc[nt][r]);
    }
  }
}

template<int NOUT, bool AF32, bool RELU>
__global__ __launch_bounds__(512) void gemm_mfma_k(const void* __restrict__ Av,
                                                   const unsigned short* __restrict__ Wt,
                                                   unsigned char* __restrict__ C, int M) {
  __shared__ unsigned short Ws[NOUT][136];
  gemm_body<NOUT, AF32, RELU>(Av, Wt, C, M, blockIdx.x, Ws);
}

// ---------------------------------------------------------------------------
// binscatter body: re-read edges, write packed (dstLocal<<17|src) into
// bin-grouped epack via LDS cursors. lds = [cur 512 | bl 64] ints.
// ---------------------------------------------------------------------------
static __device__ __forceinline__ void binscatter_body(const int* __restrict__ src,
                                                       const int* __restrict__ dst,
                                                       const int* __restrict__ histOff,
                                                       const int* __restrict__ bsum,
                                                       int nb,
                                                       unsigned* __restrict__ epack,
                                                       int E, int nbins, int bid,
                                                       int* lds) {
  int* cur = lds;
  int* bl  = lds + 512;
  local_bscan(bsum, nb, bl);
  for (int i = threadIdx.x; i < nbins; i += 512) {
    const int gi = i * 256 + bid;
    cur[i] = histOff[gi] + bl[gi >> 11];
  }
  __syncthreads();
  const int E4 = E >> 2;
  for (int i = bid * 512 + threadIdx.x; i < E4; i += 256 * 512) {
    const int4 d4 = *reinterpret_cast<const int4*>(&dst[i * 4]);
    const int4 s4 = *reinterpret_cast<const int4*>(&src[i * 4]);
    int p;
    p = atomicAdd(&cur[d4.x >> 8], 1); epack[p] = ((unsigned)(d4.x & 255) << 17) | (unsigned)s4.x;
    p = atomicAdd(&cur[d4.y >> 8], 1); epack[p] = ((unsigned)(d4.y & 255) << 17) | (unsigned)s4.y;
    p = atomicAdd(&cur[d4.z >> 8], 1); epack[p] = ((unsigned)(d4.z & 255) << 17) | (unsigned)s4.z;
    p = atomicAdd(&cur[d4.w >> 8], 1); epack[p] = ((unsigned)(d4.w & 255) << 17) | (unsigned)s4.w;
  }
  if (bid == 0 && threadIdx.x < (E & 3)) {
    const int e = E4 * 4 + threadIdx.x;
    const int d = dst[e];
    const int p = atomicAdd(&cur[d >> 8], 1);
    epack[p] = ((unsigned)(d & 255) << 17) | (unsigned)src[e];
  }
}

// ---------------------------------------------------------------------------
// Mega kernel: blocks [0,gemm_grid) = layer-1 GEMM; [gemm_grid,+256) =
// binscatter. Independent work, different bottlenecks -> overlap.
// ---------------------------------------------------------------------------
__global__ __launch_bounds__(512) void mega1_k(const float* __restrict__ x,
                                               const unsigned short* __restrict__ Wt1,
                                               unsigned char* __restrict__ H, int M,
                                               const int* __restrict__ src,
                                               const int* __restrict__ dst,
                                               const int* __restrict__ histOff,
                                               const int* __restrict__ bsum,
                                               int nb,
                                               unsigned* __restrict__ epack,
                                               int E, int nbins, int gemm_grid) {
  __shared__ unsigned short Ws[128][136];
  if ((int)blockIdx.x < gemm_grid) {
    gemm_body<128, true, false>(x, Wt1, H, M, blockIdx.x, Ws);
  } else {
    binscatter_body(src, dst, histOff, bsum, nb, epack, E, nbins,
                    blockIdx.x - gemm_grid, (int*)&Ws[0][0]);
  }
}

// ---------------------------------------------------------------------------
// hist (+ fused W transpose). bin = dst >> 8 (256 nodes/bin, <=512 bins).
// ---------------------------------------------------------------------------
__global__ __launch_bounds__(512) void histw_k(const int* __restrict__ dst,
                                               int* __restrict__ histT,
                                               int E, int nbins,
                                               const float* __restrict__ W1,
                                               const float* __restrict__ W2,
                                               const float* __restrict__ W3,
                                               unsigned short* __restrict__ Wt) {
  if (threadIdx.x < 160) {
    const int t = blockIdx.x * 160 + threadIdx.x;
    if (t < 16384) {
      Wt[t] = f2bf(W1[(t & 127) * 128 + (t >> 7)]);
    } else if (t < 32768) {
      const int u = t - 16384;
      Wt[t] = f2bf(W2[(u & 127) * 128 + (u >> 7)]);
    } else if (t < 40960) {
      const int u = t - 32768;
      Wt[t] = f2bf(W3[(u & 127) * 64 + (u >> 7)]);
    }
  }

  __shared__ int h[512];
  for (int i = threadIdx.x; i < nbins; i += 512) h[i] = 0;
  __syncthreads();
  const int E4 = E >> 2;
  for (int i = blockIdx.x * 512 + threadIdx.x; i < E4; i += 256 * 512) {
    const int4 d4 = *reinterpret_cast<const int4*>(&dst[i * 4]);
    atomicAdd(&h[d4.x >> 8], 1);
    atomicAdd(&h[d4.y >> 8], 1);
    atomicAdd(&h[d4.z >> 8], 1);
    atomicAdd(&h[d4.w >> 8], 1);
  }
  if (blockIdx.x == 0 && threadIdx.x < (E & 3))
    atomicAdd(&h[dst[E4 * 4 + threadIdx.x] >> 8], 1);
  __syncthreads();
  for (int i = threadIdx.x; i < nbins; i += 512)
    histT[i * 256 + blockIdx.x] = h[i];
}

__global__ __launch_bounds__(256) void scan1_k(const int* __restrict__ in,
                                               int* __restrict__ out,
                                               int* __restrict__ bsum, int N) {
  __shared__ int ls[256];
  const int t = threadIdx.x;
  const int base = blockIdx.x * 2048 + t * 8;
  int v[8];
  if (base + 8 <= N) {
    *reinterpret_cast<int4*>(&v[0]) = *reinterpret_cast<const int4*>(&in[base]);
    *reinterpret_cast<int4*>(&v[4]) = *reinterpret_cast<const int4*>(&in[base + 4]);
  } else {
    #pragma unroll
    for (int j = 0; j < 8; ++j) v[j] = (base + j < N) ? in[base + j] : 0;
  }
  int s = 0;
  #pragma unroll
  for (int j = 0; j < 8; ++j) { const int tmp = v[j]; v[j] = s; s += tmp; }
  int x = s;
  ls[t] = x;
  __syncthreads();
  for (int off = 1; off < 256; off <<= 1) {
    int y = 0;
    if (t >= off) y = ls[t - off];
    __syncthreads();
    x += y;
    ls[t] = x;
    __syncthreads();
  }
  const int excl = x - s;
  #pragma unroll
  for (int j = 0; j < 8; ++j)
    if (base + j < N) out[base + j] = excl + v[j];
  if (t == 255) bsum[blockIdx.x] = x;
}

// binsort: one block per 256-node bin; local bscan; 256-counter LDS histogram
// + scan -> rowptr, then LDS-cursor scatter of src into col.
__global__ __launch_bounds__(512) void binsort_k(const unsigned* __restrict__ epack,
                                                 const int* __restrict__ histOff,
                                                 const int* __restrict__ bsum,
                                                 int nb,
                                                 int* __restrict__ rowptr,
                                                 int* __restrict__ col,
                                                 int N, int E, int nbins) {
  __shared__ int hist[256];
  __shared__ int ls[256];
  __shared__ int cur[256];
  __shared__ int bl[64];
  const int b = blockIdx.x;
  const int t = threadIdx.x;
  local_bscan(bsum, nb, bl);
  const int i0 = b * 256;
  const int beg = histOff[i0] + bl[i0 >> 11];
  int end = E;
  if (b + 1 < nbins) {
    const int i1 = (b + 1) * 256;
    end = histOff[i1] + bl[i1 >> 11];
  }

  if (t < 256) hist[t] = 0;
  __syncthreads();
  for (int j = beg + t; j < end; j += 512)
    atomicAdd(&hist[epack[j] >> 17], 1);
  __syncthreads();

  int v = 0, x = 0;
  if (t < 256) { v = hist[t]; x = v; ls[t] = x; }
  __syncthreads();
  for (int off = 1; off < 256; off <<= 1) {
    int y = 0;
    if (t < 256 && t >= off) y = ls[t - off];
    __syncthreads();
    if (t < 256) { x += y; ls[t] = x; }
    __syncthreads();
  }
  if (t < 256) {
    const int excl = x - v;
    cur[t] = excl;
    const int g = b * 256 + t;
    if (g <= N) rowptr[g] = beg + excl;
  }
  if (b == nbins - 1 && t == 0) rowptr[N] = E;
  __syncthreads();
  for (int j = beg + t; j < end; j += 512) {
    const unsigned p = epack[j];
    const int pos = atomicAdd(&cur[p >> 17], 1);
    col[beg + pos] = (int)(p & 0x1ffffu);
  }
}

// ---------------------------------------------------------------------------
// Gather-aggregate, D=128 fp8 rows (128B). Quarter-wave per edge; lane loads
// uint2 (8 fp8), 16 lanes cover a row. 16-edge main loop = 4 loads/lane.
// ---------------------------------------------------------------------------
__global__ __launch_bounds__(256) void gather128_k(const uint2* __restrict__ H64,
                                                   const int* __restrict__ rowptr,
                                                   const int* __restrict__ col,
                                                   unsigned* __restrict__ out, int N) {
  const int w = (int)((blockIdx.x * 256u + threadIdx.x) >> 6);
  const int lane = threadIdx.x & 63;
  const int q = lane >> 4;                // quarter 0..3
  const int l4 = lane & 15;               // uint2 index within row (16 x 8B = 128B)
  if (w >= N) return;
  const int beg = __builtin_amdgcn_readfirstlane(rowptr[w]);
  const int end = __builtin_amdgcn_readfirstlane(rowptr[w + 1]);

  float4 a0A = make_float4(0.f, 0.f, 0.f, 0.f), a0B = make_float4(0.f, 0.f, 0.f, 0.f);
  float4 a1A = make_float4(0.f, 0.f, 0.f, 0.f), a1B = make_float4(0.f, 0.f, 0.f, 0.f);

  int e = beg;
  for (; e + 16 <= end; e += 16) {
    const int s0 = col[e + q];
    const int s1 = col[e + 4 + q];
    const int s2 = col[e + 8 + q];
    const int s3 = col[e + 12 + q];
    const uint2 u0 = H64[(size_t)s0 * 16 + l4];
    const uint2 u1 = H64[(size_t)s1 * 16 + l4];
    const uint2 u2 = H64[(size_t)s2 * 16 + l4];
    const uint2 u3 = H64[(size_t)s3 * 16 + l4];
    float4 v;
    v = fp8x4_to_f32(u0.x); a0A.x += v.x; a0A.y += v.y; a0A.z += v.z; a0A.w += v.w;
    v = fp8x4_to_f32(u0.y); a0B.x += v.x; a0B.y += v.y; a0B.z += v.z; a0B.w += v.w;
    v = fp8x4_to_f32(u1.x); a1A.x += v.x; a1A.y += v.y; a1A.z += v.z; a1A.w += v.w;
    v = fp8x4_to_f32(u1.y); a1B.x += v.x; a1B.y += v.y; a1B.z += v.z; a1B.w += v.w;
    v = fp8x4_to_f32(u2.x); a0A.x += v.x; a0A.y += v.y; a0A.z += v.z; a0A.w += v.w;
    v = fp8x4_to_f32(u2.y); a0B.x += v.x; a0B.y += v.y; a0B.z += v.z; a0B.w += v.w;
    v = fp8x4_to_f32(u3.x); a1A.x += v.x; a1A.y += v.y; a1A.z += v.z; a1A.w += v.w;
    v = fp8x4_to_f32(u3.y); a1B.x += v.x; a1B.y += v.y; a1B.z += v.z; a1B.w += v.w;
  }
  for (; e + 4 <= end; e += 4) {
    const uint2 u = H64[(size_t)col[e + q] * 16 + l4];
    float4 v;
    v = fp8x4_to_f32(u.x); a0A.x += v.x; a0A.y += v.y; a0A.z += v.z; a0A.w += v.w;
    v = fp8x4_to_f32(u.y); a0B.x += v.x; a0B.y += v.y; a0B.z += v.z; a0B.w += v.w;
  }
  if (q < end - e) {
    const uint2 u = H64[(size_t)col[e + q] * 16 + l4];
    float4 v;
    v = fp8x4_to_f32(u.x); a1A.x += v.x; a1A.y += v.y; a1A.z += v.z; a1A.w += v.w;
    v = fp8x4_to_f32(u.y); a1B.x += v.x; a1B.y += v.y; a1B.z += v.z; a1B.w += v.w;
  }

  float4 aA, aB;
  aA.x = a0A.x + a1A.x; aA.y = a0A.y + a1A.y;
  aA.z = a0A.z + a1A.z; aA.w = a0A.w + a1A.w;
  aB.x = a0B.x + a1B.x; aB.y = a0B.y + a1B.y;
  aB.z = a0B.z + a1B.z; aB.w = a0B.w + a1B.w;

  aA.x += __shfl_xor(aA.x, 16, 64); aA.x += __shfl_xor(aA.x, 32, 64);
  aA.y += __shfl_xor(aA.y, 16, 64); aA.y += __shfl_xor(aA.y, 32, 64);
  aA.z += __shfl_xor(aA.z, 16, 64); aA.z += __shfl_xor(aA.z, 32, 64);
  aA.w += __shfl_xor(aA.w, 16, 64); aA.w += __shfl_xor(aA.w, 32, 64);
  aB.x += __shfl_xor(aB.x, 16, 64); aB.x += __shfl_xor(aB.x, 32, 64);
  aB.y += __shfl_xor(aB.y, 16, 64); aB.y += __shfl_xor(aB.y, 32, 64);
  aB.z += __shfl_xor(aB.z, 16, 64); aB.z += __shfl_xor(aB.z, 32, 64);
  aB.w += __shfl_xor(aB.w, 16, 64); aB.w += __shfl_xor(aB.w, 32, 64);

  if (q == 0) {
    const uint4 pk = make_uint4(pack_bf16x2(aA.x, aA.y), pack_bf16x2(aA.z, aA.w),
                                pack_bf16x2(aB.x, aB.y), pack_bf16x2(aB.z, aB.w));
    *reinterpret_cast<uint4*>(&out[(size_t)w * 64 + l4 * 4]) = pk;
  }
}

// ---------------------------------------------------------------------------
// Gather-aggregate D=64 fp8 rows (64B) + fused log_softmax.
// ---------------------------------------------------------------------------
__global__ __launch_bounds__(256) void gather64lsm_k(const unsigned* __restrict__ H32,
                                                     const int* __restrict__ rowptr,
                                                     const int* __restrict__ col,
                                                     float* __restrict__ out, int N) {
  const int w = (int)((blockIdx.x * 256u + threadIdx.x) >> 6);
  const int lane = threadIdx.x & 63;
  const int q = lane >> 4;
  const int l4 = lane & 15;
  if (w >= N) return;
  const int beg = __builtin_amdgcn_readfirstlane(rowptr[w]);
  const int end = __builtin_amdgcn_readfirstlane(rowptr[w + 1]);

  float4 acc0 = make_float4(0.f, 0.f, 0.f, 0.f);
  float4 acc1 = make_float4(0.f, 0.f, 0.f, 0.f);

  int e = beg;
  for (; e + 16 <= end; e += 16) {
    const int s0 = col[e + q];
    const int s1 = col[e + 4 + q];
    const int s2 = col[e + 8 + q];
    const int s3 = col[e + 12 + q];
    const unsigned u0 = H32[(size_t)s0 * 16 + l4];
    const unsigned u1 = H32[(size_t)s1 * 16 + l4];
    const unsigned u2 = H32[(size_t)s2 * 16 + l4];
    const unsigned u3 = H32[(size_t)s3 * 16 + l4];
    float4 v;
    v = fp8x4_to_f32(u0); acc0.x += v.x; acc0.y += v.y; acc0.z += v.z; acc0.w += v.w;
    v = fp8x4_to_f32(u1); acc1.x += v.x; acc1.y += v.y; acc1.z += v.z; acc1.w += v.w;
    v = fp8x4_to_f32(u2); acc0.x += v.x; acc0.y += v.y; acc0.z += v.z; acc0.w += v.w;
    v = fp8x4_to_f32(u3); acc1.x += v.x; acc1.y += v.y; acc1.z += v.z; acc1.w += v.w;
  }
  for (; e + 8 <= end; e += 8) {
    const int s0 = col[e + q];
    const int s1 = col[e + 4 + q];
    const float4 v0 = fp8x4_to_f32(H32[(size_t)s0 * 16 + l4]);
    const float4 v1 = fp8x4_to_f32(H32[(size_t)s1 * 16 + l4]);
    acc0.x += v0.x; acc0.y += v0.y; acc0.z += v0.z; acc0.w += v0.w;
    acc1.x += v1.x; acc1.y += v1.y; acc1.z += v1.z; acc1.w += v1.w;
  }
  if (e + 4 <= end) {
    const float4 v = fp8x4_to_f32(H32[(size_t)col[e + q] * 16 + l4]);
    acc0.x += v.x; acc0.y += v.y; acc0.z += v.z; acc0.w += v.w;
    e += 4;
  }
  if (e + q < end) {
    const float4 v = fp8x4_to_f32(H32[(size_t)col[e + q] * 16 + l4]);
    acc1.x += v.x; acc1.y += v.y; acc1.z += v.z; acc1.w += v.w;
  }

  float4 a;
  a.x = acc0.x + acc1.x;
  a.y = acc0.y + acc1.y;
  a.z = acc0.z + acc1.z;
  a.w = acc0.w + acc1.w;
  a.x += __shfl_xor(a.x, 16, 64); a.x += __shfl_xor(a.x, 32, 64);
  a.y += __shfl_xor(a.y, 16, 64); a.y += __shfl_xor(a.y, 32, 64);
  a.z += __shfl_xor(a.z, 16, 64); a.z += __shfl_xor(a.z, 32, 64);
  a.w += __shfl_xor(a.w, 16, 64); a.w += __shfl_xor(a.w, 32, 64);

  float m = fmaxf(fmaxf(a.x, a.y), fmaxf(a.z, a.w));
  #pragma unroll
  for (int o = 8; o > 0; o >>= 1) m = fmaxf(m, __shfl_xor(m, o, 64));
  float s = __expf(a.x - m) + __expf(a.y - m) + __expf(a.z - m) + __expf(a.w - m);
  #pragma unroll
  for (int o = 8; o > 0; o >>= 1) s += __shfl_xor(s, o, 64);
  const float ls = __logf(s);

  if (lane < 16) {
    *reinterpret_cast<float4*>(&out[(size_t)w * 64 + l4 * 4]) =
        make_float4(a.x - m - ls, a.y - m - ls, a.z - m - ls, a.w - m - ls);
  }
}

extern "C" void kernel_launch(void* const* d_in, const int* in_sizes, int n_in,
                              void* d_out, int out_size, void* d_ws, size_t ws_size,
                              hipStream_t stream) {
  const float* x  = (const float*)d_in[0];
  const int*   ei = (const int*)d_in[1];
  const float* W1 = (const float*)d_in[2];
  const float* W2 = (const float*)d_in[3];
  const float* W3 = (const float*)d_in[4];
  float* out = (float*)d_out;

  const int N = in_sizes[0] / KDIM;       // 100000
  const int E = in_sizes[1] / 2;          // 1600000
  const int* src = ei;
  const int* dst = ei + E;

  const int nbins = (N + 255) / 256;      // 391
  const int ncells = nbins * 256;         // 100096
  const int scan_blocks = (ncells + 2047) / 2048;  // 49

  // Workspace layout (all chunks 16B-aligned)
  unsigned char* H = (unsigned char*)d_ws;              // [N,128] fp8
  unsigned* AGGp = (unsigned*)(H + (size_t)N * 128);    // [N,64] packed bf16 pairs
  unsigned short* Wt1 = (unsigned short*)(AGGp + (size_t)N * 64);  // [128,128]
  unsigned short* Wt2 = Wt1 + 128 * 128;                // [128,128]
  unsigned short* Wt3 = Wt2 + 128 * 128;                // [64,128]
  int* col     = (int*)(Wt3 + 64 * 128);                // [E]
  int* rowptr  = col + E;                               // [N+8]
  int* histT   = rowptr + (N + 8);                      // [<=131072]
  int* histOff = histT + 131072;                        // [<=131072]
  int* bsum2   = histOff + 131072;                      // [64]
  // epack (u32[E]) aliases AGGp (dead until layer-1 gather): E*4B <= N*64*4B
  unsigned* epack = (unsigned*)AGGp;

  const int gemm_grid = (N + 127) / 128;
  const int gather_grid = (N + 3) / 4;

  // ---- CSR build (with fused W transpose), then GEMM1 || binscatter ----
  histw_k<<<256, 512, 0, stream>>>(dst, histT, E, nbins, W1, W2, W3, Wt1);
  scan1_k<<<scan_blocks, 256, 0, stream>>>(histT, histOff, bsum2, ncells);
  mega1_k<<<gemm_grid + 256, 512, 0, stream>>>(x, Wt1, H, N, src, dst,
                                               histOff, bsum2, scan_blocks, epack,
                                               E, nbins, gemm_grid);
  binsort_k<<<nbins, 512, 0, stream>>>(epack, histOff, bsum2, scan_blocks,
                                       rowptr, col, N, E, nbins);

  // ---- layer 1 gather ----
  gather128_k<<<gather_grid, 256, 0, stream>>>((const uint2*)H, rowptr, col, AGGp, N);

  // ---- layer 2 ----
  gemm_mfma_k<128, false, true><<<gemm_grid, 512, 0, stream>>>(AGGp, Wt2, H, N);
  gather128_k<<<gather_grid, 256, 0, stream>>>((const uint2*)H, rowptr, col, AGGp, N);

  // ---- layer 3 (+ fused log_softmax) ----
  gemm_mfma_k<64, false, true><<<gemm_grid, 512, 0, stream>>>(AGGp, Wt3, H, N);
  gather64lsm_k<<<gather_grid, 256, 0, stream>>>((const unsigned*)H, rowptr, col, out, N);
}